// Round 1
// baseline (4106.107 us; speedup 1.0000x reference)
//
#include <hip/hip_runtime.h>
#include <math.h>

#define S_LEN 2048
#define DMODEL 2560
#define NH 32
#define NKV 8
#define HD 128
#define QDIM (NH*HD)     // 4096
#define KVDIM (NKV*HD)   // 1024
#define ROPE_THETA 5000000.0

// XOR swizzle: spread rows across LDS banks. Returns XOR mask for float index
// (touches bits 2..4 -> permutes 16B slots within a 128B span). Involution.
__device__ __forceinline__ int swz(int row) {
    return (((row & 7) ^ ((row >> 3) & 7)) << 2);
}

// ---------------------------------------------------------------------------
// RoPE tables: cos/sin computed in fp64 (large-angle range reduction matters)
// ---------------------------------------------------------------------------
__global__ void rope_tables(const int* __restrict__ pos_ids,
                            float* __restrict__ cost, float* __restrict__ sint) {
    int idx = blockIdx.x * 256 + threadIdx.x;   // S_LEN*64
    if (idx >= S_LEN * 64) return;
    int s = idx >> 6, j = idx & 63;
    double inv = pow((double)ROPE_THETA, -(double)j / 64.0);
    double ang = (double)pos_ids[s] * inv;
    cost[idx] = (float)cos(ang);
    sint[idx] = (float)sin(ang);
}

// q layout: [s][h*128+d]
__global__ void rope_apply_q(float* __restrict__ q,
                             const float* __restrict__ cost, const float* __restrict__ sint) {
    int idx = blockIdx.x * 256 + threadIdx.x;   // S_LEN*NH*64
    int j = idx & 63;
    int h = (idx >> 6) & 31;
    int s = idx >> 11;
    float c = cost[(s << 6) + j], sn = sint[(s << 6) + j];
    size_t base = (size_t)s * QDIM + (size_t)h * HD;
    float x1 = q[base + j], x2 = q[base + 64 + j];
    q[base + j]      = x1 * c - x2 * sn;
    q[base + 64 + j] = x2 * c + x1 * sn;
}

// k layout: [h][s][128]
__global__ void rope_apply_k(float* __restrict__ k,
                             const float* __restrict__ cost, const float* __restrict__ sint) {
    int idx = blockIdx.x * 256 + threadIdx.x;   // NKV*S_LEN*64
    int j = idx & 63;
    int s = (idx >> 6) & 2047;
    int h = idx >> 17;
    float c = cost[(s << 6) + j], sn = sint[(s << 6) + j];
    size_t base = (size_t)h * S_LEN * HD + (size_t)s * HD;
    float x1 = k[base + j], x2 = k[base + 64 + j];
    k[base + j]      = x1 * c - x2 * sn;
    k[base + 64 + j] = x2 * c + x1 * sn;
}

// ---------------------------------------------------------------------------
// fp32 NT GEMM: C[M][N] = sum_k A[M][K]*B[N][K]. BM=BN=64, BK=32, 256 thr, 4x4.
// MODE 0: C row-major [M][N].  MODE 1: kv-cache layout [n>>7][m][n&127].
// ---------------------------------------------------------------------------
template<int MODE>
__global__ __launch_bounds__(256)
void sgemm_nt(const float* __restrict__ A, const float* __restrict__ B,
              float* __restrict__ C, int M, int N, int K) {
    __shared__ __align__(16) float As[64 * 32];
    __shared__ __align__(16) float Bs[64 * 32];
    const int tid = threadIdx.x;
    const int ty = tid >> 4, tx = tid & 15;
    const int m0 = blockIdx.y * 64, n0 = blockIdx.x * 64;
    const int prow = tid >> 3;          // 0..31
    const int pc4  = (tid & 7) << 2;    // 0,4,..,28

    float acc[4][4] = {};

    for (int k0 = 0; k0 < K; k0 += 32) {
        __syncthreads();
        #pragma unroll
        for (int r = 0; r < 2; ++r) {
            int row = prow + r * 32;
            float4 av = *(const float4*)&A[(size_t)(m0 + row) * K + k0 + pc4];
            float4 bv = *(const float4*)&B[(size_t)(n0 + row) * K + k0 + pc4];
            *(float4*)&As[(row * 32 + pc4) ^ swz(row)] = av;
            *(float4*)&Bs[(row * 32 + pc4) ^ swz(row)] = bv;
        }
        __syncthreads();
        #pragma unroll
        for (int kk4 = 0; kk4 < 8; ++kk4) {
            float4 a4[4], b4[4];
            #pragma unroll
            for (int i = 0; i < 4; ++i) {
                int row = 4 * ty + i;
                a4[i] = *(const float4*)&As[(row * 32 + kk4 * 4) ^ swz(row)];
            }
            #pragma unroll
            for (int j = 0; j < 4; ++j) {
                int row = 4 * tx + j;
                b4[j] = *(const float4*)&Bs[(row * 32 + kk4 * 4) ^ swz(row)];
            }
            #pragma unroll
            for (int i = 0; i < 4; ++i)
                #pragma unroll
                for (int j = 0; j < 4; ++j)
                    acc[i][j] += a4[i].x * b4[j].x + a4[i].y * b4[j].y
                               + a4[i].z * b4[j].z + a4[i].w * b4[j].w;
        }
    }

    #pragma unroll
    for (int i = 0; i < 4; ++i) {
        int m = m0 + 4 * ty + i;
        #pragma unroll
        for (int j = 0; j < 4; ++j) {
            int n = n0 + 4 * tx + j;
            if (MODE == 0)
                C[(size_t)m * N + n] = acc[i][j];
            else
                C[(size_t)(n >> 7) * (S_LEN * HD) + (size_t)m * HD + (n & 127)] = acc[i][j];
        }
    }
}

// ---------------------------------------------------------------------------
// Flash attention, fp32, causal. BQ=BKV=64, 512 threads.
// q: [s][h*128+d], k/v: [kvh][s][128], out ao: [s][h*128+d]
// ---------------------------------------------------------------------------
__global__ __launch_bounds__(512)
void attn_fwd(const float* __restrict__ q, const float* __restrict__ kc,
              const float* __restrict__ vc, float* __restrict__ ao) {
    const int qt  = blockIdx.x;   // 0..31
    const int h   = blockIdx.y;   // 0..31
    const int kvh = h >> 2;
    const int tid = threadIdx.x;
    const int ty  = tid >> 4;     // 0..31
    const int tx  = tid & 15;     // 0..15

    __shared__ __align__(16) float Qs[64 * 128];
    __shared__ __align__(16) float Ks[64 * 128];
    __shared__ __align__(16) float Vs[64 * 128];
    __shared__ float Ps[64 * 67];
    __shared__ float m_s[64], l_s[64], corr_s[64];

    // stage Q tile (once)
    const float* qbase = q + (size_t)(qt * 64) * QDIM + (size_t)h * HD;
    for (int p = tid; p < 64 * 32; p += 512) {
        int row = p >> 5, c4 = (p & 31) << 2;
        float4 v = *(const float4*)&qbase[(size_t)row * QDIM + c4];
        *(float4*)&Qs[(row * 128 + c4) ^ swz(row)] = v;
    }
    if (tid < 64) { m_s[tid] = -1e30f; l_s[tid] = 0.f; }

    float acc[2][8] = {};
    const int qrow0 = qt * 64;

    for (int kt = 0; kt <= qt; ++kt) {
        __syncthreads();  // prev-iter readers of Ks/Vs/Ps done; Qs/m/l ready on iter 0
        // stage K,V tiles
        const float* kbase = kc + (size_t)kvh * S_LEN * HD + (size_t)(kt * 64) * HD;
        const float* vbase = vc + (size_t)kvh * S_LEN * HD + (size_t)(kt * 64) * HD;
        for (int p = tid; p < 64 * 32; p += 512) {
            int row = p >> 5, c4 = (p & 31) << 2;
            float4 kv4 = *(const float4*)&kbase[(size_t)row * HD + c4];
            float4 vv4 = *(const float4*)&vbase[(size_t)row * HD + c4];
            *(float4*)&Ks[(row * 128 + c4) ^ swz(row)] = kv4;
            *(float4*)&Vs[(row * 128 + c4) ^ swz(row)] = vv4;
        }
        __syncthreads();

        // S = Q K^T / sqrt(HD), 2x4 microtile per thread
        float accs[2][4] = {};
        #pragma unroll 4
        for (int d4 = 0; d4 < 32; ++d4) {
            float4 a4[2], b4[4];
            #pragma unroll
            for (int i = 0; i < 2; ++i) {
                int row = 2 * ty + i;
                a4[i] = *(const float4*)&Qs[(row * 128 + d4 * 4) ^ swz(row)];
            }
            #pragma unroll
            for (int j = 0; j < 4; ++j) {
                int row = 4 * tx + j;
                b4[j] = *(const float4*)&Ks[(row * 128 + d4 * 4) ^ swz(row)];
            }
            #pragma unroll
            for (int i = 0; i < 2; ++i)
                #pragma unroll
                for (int j = 0; j < 4; ++j)
                    accs[i][j] += a4[i].x * b4[j].x + a4[i].y * b4[j].y
                                + a4[i].z * b4[j].z + a4[i].w * b4[j].w;
        }
        // masked, scaled store to Ps
        const int kcol0 = kt * 64;
        #pragma unroll
        for (int i = 0; i < 2; ++i) {
            int r = 2 * ty + i;
            #pragma unroll
            for (int j = 0; j < 4; ++j) {
                int cj = 4 * tx + j;
                float sv = accs[i][j] * 0.08838834764831843f;
                if (kcol0 + cj > qrow0 + r) sv = -1e30f;
                Ps[r * 67 + cj] = sv;
            }
        }
        __syncthreads();

        // online softmax row pass (rows 0..63 by threads 0..63)
        if (tid < 64) {
            float mold = m_s[tid];
            float mx = mold;
            for (int j = 0; j < 64; ++j) mx = fmaxf(mx, Ps[tid * 67 + j]);
            float corr = expf(mold - mx);
            float sum = 0.f;
            for (int j = 0; j < 64; ++j) {
                float p = expf(Ps[tid * 67 + j] - mx);
                Ps[tid * 67 + j] = p;
                sum += p;
            }
            l_s[tid] = l_s[tid] * corr + sum;
            m_s[tid] = mx;
            corr_s[tid] = corr;
        }
        __syncthreads();

        // rescale existing accumulator, then PV
        float cr0 = corr_s[2 * ty], cr1 = corr_s[2 * ty + 1];
        #pragma unroll
        for (int cc = 0; cc < 8; ++cc) { acc[0][cc] *= cr0; acc[1][cc] *= cr1; }

        #pragma unroll 4
        for (int j = 0; j < 64; ++j) {
            float p0 = Ps[(2 * ty) * 67 + j];
            float p1 = Ps[(2 * ty + 1) * 67 + j];
            float4 va = *(const float4*)&Vs[(j * 128 + 8 * tx) ^ swz(j)];
            float4 vb = *(const float4*)&Vs[(j * 128 + 8 * tx + 4) ^ swz(j)];
            float vv[8] = {va.x, va.y, va.z, va.w, vb.x, vb.y, vb.z, vb.w};
            #pragma unroll
            for (int cc = 0; cc < 8; ++cc) {
                acc[0][cc] += p0 * vv[cc];
                acc[1][cc] += p1 * vv[cc];
            }
        }
    }

    // epilogue: divide by l, write ao[s][h*128+col]
    float r0 = 1.f / l_s[2 * ty], r1 = 1.f / l_s[2 * ty + 1];
    float4 o0a = make_float4(acc[0][0] * r0, acc[0][1] * r0, acc[0][2] * r0, acc[0][3] * r0);
    float4 o0b = make_float4(acc[0][4] * r0, acc[0][5] * r0, acc[0][6] * r0, acc[0][7] * r0);
    float4 o1a = make_float4(acc[1][0] * r1, acc[1][1] * r1, acc[1][2] * r1, acc[1][3] * r1);
    float4 o1b = make_float4(acc[1][4] * r1, acc[1][5] * r1, acc[1][6] * r1, acc[1][7] * r1);
    size_t obase0 = (size_t)(qrow0 + 2 * ty)     * QDIM + (size_t)h * HD + 8 * tx;
    size_t obase1 = (size_t)(qrow0 + 2 * ty + 1) * QDIM + (size_t)h * HD + 8 * tx;
    *(float4*)&ao[obase0]     = o0a;
    *(float4*)&ao[obase0 + 4] = o0b;
    *(float4*)&ao[obase1]     = o1a;
    *(float4*)&ao[obase1 + 4] = o1b;
}

// ---------------------------------------------------------------------------
extern "C" void kernel_launch(void* const* d_in, const int* in_sizes, int n_in,
                              void* d_out, int out_size, void* d_ws, size_t ws_size,
                              hipStream_t stream) {
    const float* x   = (const float*)d_in[0];
    const int*   pos = (const int*)d_in[1];
    const float* w_q = (const float*)d_in[2];
    const float* w_k = (const float*)d_in[3];
    const float* w_v = (const float*)d_in[4];
    const float* w_o = (const float*)d_in[5];

    float* out   = (float*)d_out;
    float* out_k = out + (size_t)S_LEN * DMODEL;            // (8,2048,128)
    float* out_v = out_k + (size_t)NKV * S_LEN * HD;

    // workspace: q (32MB) + ao (32MB) + cos/sin tables (1MB)  ~= 65MB
    float* q_ws  = (float*)d_ws;
    float* ao_ws = q_ws + (size_t)S_LEN * QDIM;
    float* cost  = ao_ws + (size_t)S_LEN * QDIM;
    float* sint  = cost + S_LEN * 64;

    // RoPE tables (fp64-accurate)
    rope_tables<<<(S_LEN * 64 + 255) / 256, 256, 0, stream>>>(pos, cost, sint);

    // projections
    sgemm_nt<0><<<dim3(QDIM / 64, S_LEN / 64), 256, 0, stream>>>(x, w_q, q_ws, S_LEN, QDIM, DMODEL);
    sgemm_nt<1><<<dim3(KVDIM / 64, S_LEN / 64), 256, 0, stream>>>(x, w_k, out_k, S_LEN, KVDIM, DMODEL);
    sgemm_nt<1><<<dim3(KVDIM / 64, S_LEN / 64), 256, 0, stream>>>(x, w_v, out_v, S_LEN, KVDIM, DMODEL);

    // RoPE (q in ws, k in-place in output cache)
    rope_apply_q<<<(S_LEN * NH * 64) / 256, 256, 0, stream>>>(q_ws, cost, sint);
    rope_apply_k<<<(NKV * S_LEN * 64) / 256, 256, 0, stream>>>(out_k, cost, sint);

    // attention
    attn_fwd<<<dim3(S_LEN / 64, NH), 512, 0, stream>>>(q_ws, out_k, out_v, ao_ws);

    // output projection
    sgemm_nt<0><<<dim3(DMODEL / 64, S_LEN / 64), 256, 0, stream>>>(ao_ws, w_o, out, S_LEN, DMODEL, QDIM);
}

// Round 2
// 696.149 us; speedup vs baseline: 5.8983x; 5.8983x over previous
//
#include <hip/hip_runtime.h>
#include <math.h>

#define S_LEN 2048
#define DMODEL 2560
#define NH 32
#define NKV 8
#define HD 128
#define QDIM (NH*HD)     // 4096
#define KVDIM (NKV*HD)   // 1024
#define ROPE_THETA 5000000.0
#define QK_SCALE 0.08838834764831843f

typedef __attribute__((ext_vector_type(8))) short s16x8;
typedef __attribute__((ext_vector_type(4))) float f32x4;
typedef unsigned short u16;

#define MFMA16(a,b,c) __builtin_amdgcn_mfma_f32_16x16x32_bf16((a),(b),(c),0,0,0)

__device__ __forceinline__ u16 f2bf(float x) {
    union { float f; unsigned u; } v; v.f = x;
    unsigned r = v.u + 0x7FFFu + ((v.u >> 16) & 1u);
    return (u16)(r >> 16);
}
__device__ __forceinline__ float bf2f(u16 h) {
    union { unsigned u; float f; } v; v.u = ((unsigned)h) << 16;
    return v.f;
}

// Swizzled LDS index: tile row-major [rows][CKU*8] bf16; unit = 8 bf16 (16B).
// XOR row&7 into unit index -> conflict-free b128 column-of-rows reads.
__device__ __forceinline__ int lsw(int row, int kb, int CKU) {
    return (((row * CKU + kb) ^ (row & 7)) << 3);   // u16 element index
}

// ---------------------------------------------------------------------------
// RoPE tables (fp64-accurate range reduction)
// ---------------------------------------------------------------------------
__global__ void rope_tables(const int* __restrict__ pos_ids,
                            float* __restrict__ cost, float* __restrict__ sint) {
    int idx = blockIdx.x * 256 + threadIdx.x;
    if (idx >= S_LEN * 64) return;
    int s = idx >> 6, j = idx & 63;
    double inv = pow((double)ROPE_THETA, -(double)j / 64.0);
    double ang = (double)pos_ids[s] * inv;
    cost[idx] = (float)cos(ang);
    sint[idx] = (float)sin(ang);
}

__global__ void rope_apply_q(float* __restrict__ q,
                             const float* __restrict__ cost, const float* __restrict__ sint) {
    int idx = blockIdx.x * 256 + threadIdx.x;   // S_LEN*NH*64
    int j = idx & 63;
    int h = (idx >> 6) & 31;
    int s = idx >> 11;
    float c = cost[(s << 6) + j], sn = sint[(s << 6) + j];
    size_t base = (size_t)s * QDIM + (size_t)h * HD;
    float x1 = q[base + j], x2 = q[base + 64 + j];
    q[base + j]      = x1 * c - x2 * sn;
    q[base + 64 + j] = x2 * c + x1 * sn;
}

__global__ void rope_apply_k(float* __restrict__ k,
                             const float* __restrict__ cost, const float* __restrict__ sint) {
    int idx = blockIdx.x * 256 + threadIdx.x;   // NKV*S_LEN*64
    int j = idx & 63;
    int s = (idx >> 6) & 2047;
    int h = idx >> 17;
    float c = cost[(s << 6) + j], sn = sint[(s << 6) + j];
    size_t base = (size_t)h * S_LEN * HD + (size_t)s * HD;
    float x1 = k[base + j], x2 = k[base + 64 + j];
    k[base + j]      = x1 * c - x2 * sn;
    k[base + 64 + j] = x2 * c + x1 * sn;
}

// ---------------------------------------------------------------------------
// split fp32 -> bf16 hi/lo (with optional scale)
// ---------------------------------------------------------------------------
__global__ void split2(const float* __restrict__ in, u16* __restrict__ hi,
                       u16* __restrict__ lo, size_t n4, float scale) {
    size_t i = (size_t)blockIdx.x * 256 + threadIdx.x;
    if (i >= n4) return;
    float4 v = ((const float4*)in)[i];
    float a[4] = {v.x * scale, v.y * scale, v.z * scale, v.w * scale};
    u16 hh[4], ll[4];
    #pragma unroll
    for (int j = 0; j < 4; ++j) {
        hh[j] = f2bf(a[j]);
        ll[j] = f2bf(a[j] - bf2f(hh[j]));
    }
    ((uint2*)hi)[i] = make_uint2((unsigned)hh[0] | ((unsigned)hh[1] << 16),
                                 (unsigned)hh[2] | ((unsigned)hh[3] << 16));
    ((uint2*)lo)[i] = make_uint2((unsigned)ll[0] | ((unsigned)ll[1] << 16),
                                 (unsigned)ll[2] | ((unsigned)ll[3] << 16));
}

// ---------------------------------------------------------------------------
// Split-bf16 MFMA GEMM (NT): C[m][n] = sum_k A[m][k]B[n][k], 128x128 tile, BK=64.
// mode 0: C1 row-major [M][N]. mode 1: fused KV -> kv-cache layout (+vt for V).
// ---------------------------------------------------------------------------
__global__ __launch_bounds__(256, 2)
void gemm_split(const u16* __restrict__ Ah, const u16* __restrict__ Al,
                const u16* __restrict__ B1h, const u16* __restrict__ B1l,
                const u16* __restrict__ B2h, const u16* __restrict__ B2l,
                float* __restrict__ C1, float* __restrict__ C2, u16* __restrict__ CT,
                int N, int K, int mode) {
    __shared__ u16 Ahs[128 * 64], Als[128 * 64], Bhs[128 * 64], Bls[128 * 64];
    const int tid = threadIdx.x;
    const int lane = tid & 63, w = tid >> 6;
    const int q4 = lane >> 4, r15 = lane & 15;
    const int m0 = blockIdx.y * 128;
    const int wm = (w >> 1) * 64, wn = (w & 1) * 64;

    const u16 *Bh, *Bl;
    float* C;
    int n0;
    bool wvt = false;
    if (mode == 0) {
        Bh = B1h; Bl = B1l; C = C1; n0 = blockIdx.x * 128;
    } else {
        bool isv = blockIdx.x >= 8;
        Bh = isv ? B2h : B1h; Bl = isv ? B2l : B1l;
        C = isv ? C2 : C1;
        n0 = (blockIdx.x & 7) * 128;
        wvt = isv;
    }

    f32x4 acc[4][4];
    #pragma unroll
    for (int i = 0; i < 4; ++i)
        #pragma unroll
        for (int j = 0; j < 4; ++j) acc[i][j] = (f32x4)(0.0f);

    const int srow = tid >> 3, skb = tid & 7;
    for (int k0 = 0; k0 < K; k0 += 64) {
        __syncthreads();
        #pragma unroll
        for (int p = 0; p < 4; ++p) {
            int row = srow + p * 32;
            size_t ga = (size_t)(m0 + row) * K + k0 + skb * 8;
            size_t gb = (size_t)(n0 + row) * K + k0 + skb * 8;
            int li = lsw(row, skb, 8);
            *(int4*)&Ahs[li] = *(const int4*)(Ah + ga);
            *(int4*)&Als[li] = *(const int4*)(Al + ga);
            *(int4*)&Bhs[li] = *(const int4*)(Bh + gb);
            *(int4*)&Bls[li] = *(const int4*)(Bl + gb);
        }
        __syncthreads();
        #pragma unroll
        for (int kh = 0; kh < 2; ++kh) {
            s16x8 ah[4], al[4], bh[4], bl[4];
            int kb = kh * 4 + q4;
            #pragma unroll
            for (int i = 0; i < 4; ++i) {
                ah[i] = *(const s16x8*)&Ahs[lsw(wm + i * 16 + r15, kb, 8)];
                al[i] = *(const s16x8*)&Als[lsw(wm + i * 16 + r15, kb, 8)];
                bh[i] = *(const s16x8*)&Bhs[lsw(wn + i * 16 + r15, kb, 8)];
                bl[i] = *(const s16x8*)&Bls[lsw(wn + i * 16 + r15, kb, 8)];
            }
            #pragma unroll
            for (int i = 0; i < 4; ++i)
                #pragma unroll
                for (int j = 0; j < 4; ++j) {
                    acc[i][j] = MFMA16(ah[i], bh[j], acc[i][j]);
                    acc[i][j] = MFMA16(ah[i], bl[j], acc[i][j]);
                    acc[i][j] = MFMA16(al[i], bh[j], acc[i][j]);
                }
        }
    }

    // epilogue: D layout col = lane&15, row = (lane>>4)*4 + r  [m89-verified]
    #pragma unroll
    for (int i = 0; i < 4; ++i) {
        #pragma unroll
        for (int j = 0; j < 4; ++j) {
            int col = n0 + wn + j * 16 + r15;
            #pragma unroll
            for (int r = 0; r < 4; ++r) {
                int row = m0 + wm + i * 16 + q4 * 4 + r;
                float val = acc[i][j][r];
                if (mode == 0) {
                    C[(size_t)row * N + col] = val;
                } else {
                    int hh = col >> 7, d = col & 127;
                    C[((size_t)hh * S_LEN + row) * HD + d] = val;
                    if (wvt) CT[((size_t)hh * HD + d) * S_LEN + row] = f2bf(val);
                }
            }
        }
    }
}

// ---------------------------------------------------------------------------
// MFMA flash attention. Block: 4 waves, 64 q-rows (16/wave), one head.
// qh/ql: [2048][4096] bf16 (pre-scaled); kh/kl: [8][2048][128]; vt: [8][128][2048]
// ---------------------------------------------------------------------------
__global__ __launch_bounds__(256, 2)
void attn_mfma(const u16* __restrict__ qh, const u16* __restrict__ ql,
               const u16* __restrict__ kh, const u16* __restrict__ kl,
               const u16* __restrict__ vt, float* __restrict__ ao) {
    const int qt = blockIdx.x, h = blockIdx.y, kvh = h >> 2;
    const int tid = threadIdx.x, lane = tid & 63, w = tid >> 6;
    const int q4 = lane >> 4, r15 = lane & 15;

    __shared__ u16 Khs[64 * 128], Kls[64 * 128];  // [64][128] swizzled, CKU=16
    __shared__ u16 Vts[128 * 64];                 // [128][64] swizzled, CKU=8
    __shared__ u16 Ps[64 * 64];                   // [64][64]  swizzled, CKU=8

    // Q fragments in registers (A-layout: row = r15, k = db*32 + q4*8 + jj)
    s16x8 qfh[4], qfl[4];
    {
        size_t qrow = (size_t)qt * 64 + w * 16 + r15;
        const u16* qb  = qh + qrow * QDIM + h * HD + q4 * 8;
        const u16* qb2 = ql + qrow * QDIM + h * HD + q4 * 8;
        #pragma unroll
        for (int db = 0; db < 4; ++db) {
            qfh[db] = *(const s16x8*)(qb + db * 32);
            qfl[db] = *(const s16x8*)(qb2 + db * 32);
        }
    }

    f32x4 acco[8];
    #pragma unroll
    for (int db = 0; db < 8; ++db) acco[db] = (f32x4)(0.0f);
    float mrow[4] = {-1e30f, -1e30f, -1e30f, -1e30f};
    float lrow[4] = {0.f, 0.f, 0.f, 0.f};

    const int srow16 = tid >> 4, skb16 = tid & 15;
    const int srow8 = tid >> 3, skb8 = tid & 7;

    for (int kt = 0; kt <= qt; ++kt) {
        __syncthreads();
        #pragma unroll
        for (int p = 0; p < 4; ++p) {   // K hi/lo: [64][128]
            int row = srow16 + p * 16;
            size_t g = ((size_t)kvh * S_LEN + (size_t)kt * 64 + row) * HD + skb16 * 8;
            int li = lsw(row, skb16, 16);
            *(int4*)&Khs[li] = *(const int4*)(kh + g);
            *(int4*)&Kls[li] = *(const int4*)(kl + g);
        }
        #pragma unroll
        for (int p = 0; p < 4; ++p) {   // Vt: [128][64]
            int row = srow8 + p * 32;
            size_t g = ((size_t)kvh * HD + row) * S_LEN + (size_t)kt * 64 + skb8 * 8;
            *(int4*)&Vts[lsw(row, skb8, 8)] = *(const int4*)(vt + g);
        }
        __syncthreads();

        // S = Q K^T (split: qh*kh + qh*kl + ql*kh)
        f32x4 sf[4];
        #pragma unroll
        for (int kf = 0; kf < 4; ++kf) sf[kf] = (f32x4)(0.0f);
        #pragma unroll
        for (int db = 0; db < 4; ++db) {
            int kb = db * 4 + q4;
            #pragma unroll
            for (int kf = 0; kf < 4; ++kf) {
                s16x8 bh = *(const s16x8*)&Khs[lsw(kf * 16 + r15, kb, 16)];
                s16x8 bl = *(const s16x8*)&Kls[lsw(kf * 16 + r15, kb, 16)];
                sf[kf] = MFMA16(qfh[db], bh, sf[kf]);
                sf[kf] = MFMA16(qfh[db], bl, sf[kf]);
                sf[kf] = MFMA16(qfl[db], bh, sf[kf]);
            }
        }

        // causal mask (diagonal tile only)
        if (kt == qt) {
            #pragma unroll
            for (int kf = 0; kf < 4; ++kf) {
                int col = kf * 16 + r15;
                #pragma unroll
                for (int r = 0; r < 4; ++r) {
                    int rowg = w * 16 + q4 * 4 + r;
                    if (col > rowg) sf[kf][r] = -1e30f;
                }
            }
        }

        // online softmax: rows live on 16 lanes of each quarter
        float mx[4], corr[4], rs[4];
        #pragma unroll
        for (int r = 0; r < 4; ++r)
            mx[r] = fmaxf(fmaxf(sf[0][r], sf[1][r]), fmaxf(sf[2][r], sf[3][r]));
        #pragma unroll
        for (int o = 1; o < 16; o <<= 1)
            #pragma unroll
            for (int r = 0; r < 4; ++r)
                mx[r] = fmaxf(mx[r], __shfl_xor(mx[r], o));
        #pragma unroll
        for (int r = 0; r < 4; ++r) {
            float mn = fmaxf(mrow[r], mx[r]);
            corr[r] = __expf(mrow[r] - mn);
            mrow[r] = mn;
        }
        #pragma unroll
        for (int r = 0; r < 4; ++r) {
            float s0 = __expf(sf[0][r] - mrow[r]);
            float s1 = __expf(sf[1][r] - mrow[r]);
            float s2 = __expf(sf[2][r] - mrow[r]);
            float s3 = __expf(sf[3][r] - mrow[r]);
            sf[0][r] = s0; sf[1][r] = s1; sf[2][r] = s2; sf[3][r] = s3;
            rs[r] = (s0 + s1) + (s2 + s3);
        }
        #pragma unroll
        for (int o = 1; o < 16; o <<= 1)
            #pragma unroll
            for (int r = 0; r < 4; ++r)
                rs[r] += __shfl_xor(rs[r], o);
        #pragma unroll
        for (int r = 0; r < 4; ++r) lrow[r] = lrow[r] * corr[r] + rs[r];
        #pragma unroll
        for (int db = 0; db < 8; ++db)
            #pragma unroll
            for (int r = 0; r < 4; ++r) acco[db][r] *= corr[r];

        // P -> LDS bf16 (wave-private rows; same-wave RAW, no barrier needed)
        #pragma unroll
        for (int kf = 0; kf < 4; ++kf) {
            int col = kf * 16 + r15;
            #pragma unroll
            for (int r = 0; r < 4; ++r) {
                int prow = w * 16 + q4 * 4 + r;
                Ps[lsw(prow, col >> 3, 8) + (col & 7)] = f2bf(sf[kf][r]);
            }
        }

        // O += P V
        s16x8 pa0 = *(const s16x8*)&Ps[lsw(w * 16 + r15, q4, 8)];
        s16x8 pa1 = *(const s16x8*)&Ps[lsw(w * 16 + r15, 4 + q4, 8)];
        #pragma unroll
        for (int db = 0; db < 8; ++db) {
            s16x8 vb0 = *(const s16x8*)&Vts[lsw(db * 16 + r15, q4, 8)];
            s16x8 vb1 = *(const s16x8*)&Vts[lsw(db * 16 + r15, 4 + q4, 8)];
            acco[db] = MFMA16(pa0, vb0, acco[db]);
            acco[db] = MFMA16(pa1, vb1, acco[db]);
        }
    }

    float inv[4];
    #pragma unroll
    for (int r = 0; r < 4; ++r) inv[r] = 1.0f / lrow[r];
    #pragma unroll
    for (int db = 0; db < 8; ++db)
        #pragma unroll
        for (int r = 0; r < 4; ++r) {
            size_t row = (size_t)qt * 64 + w * 16 + q4 * 4 + r;
            ao[row * QDIM + h * HD + db * 16 + r15] = acco[db][r] * inv[r];
        }
}

// ---------------------------------------------------------------------------
extern "C" void kernel_launch(void* const* d_in, const int* in_sizes, int n_in,
                              void* d_out, int out_size, void* d_ws, size_t ws_size,
                              hipStream_t stream) {
    const float* x   = (const float*)d_in[0];
    const int*   pos = (const int*)d_in[1];
    const float* w_q = (const float*)d_in[2];
    const float* w_k = (const float*)d_in[3];
    const float* w_v = (const float*)d_in[4];
    const float* w_o = (const float*)d_in[5];

    float* out   = (float*)d_out;
    float* out_k = out + (size_t)S_LEN * DMODEL;
    float* out_v = out_k + (size_t)NKV * S_LEN * HD;

    // ---- workspace arena (bytes) ----
    char* ws = (char*)d_ws;
    size_t off = 0;
    auto alloc = [&](size_t bytes) { char* p = ws + off; off += (bytes + 255) & ~255ull; return p; };
    float* cost = (float*)alloc((size_t)S_LEN * 64 * 4);
    float* sint = (float*)alloc((size_t)S_LEN * 64 * 4);
    float* Q32  = (float*)alloc((size_t)S_LEN * QDIM * 4);        // also AO32
    u16* XH = (u16*)alloc((size_t)S_LEN * DMODEL * 2);
    u16* XL = (u16*)alloc((size_t)S_LEN * DMODEL * 2);
    u16* WH = (u16*)alloc((size_t)QDIM * DMODEL * 2);             // wq / wo (and wk/wv packed)
    u16* WL = (u16*)alloc((size_t)QDIM * DMODEL * 2);
    u16* QH = (u16*)alloc((size_t)S_LEN * QDIM * 2);              // also AOH
    u16* QL = (u16*)alloc((size_t)S_LEN * QDIM * 2);              // also AOL
    u16* KH = (u16*)alloc((size_t)NKV * S_LEN * HD * 2);
    u16* KL = (u16*)alloc((size_t)NKV * S_LEN * HD * 2);
    u16* VT = (u16*)alloc((size_t)NKV * HD * S_LEN * 2);
    // wk/wv hi/lo packed into WH/WL halves
    u16* WKH = WH;                        u16* WKL = WL;
    u16* WVH = WH + (size_t)KVDIM * DMODEL; u16* WVL = WL + (size_t)KVDIM * DMODEL;

    float* AO32 = Q32;
    u16* AOH = QH; u16* AOL = QL;

    // 1. RoPE tables
    rope_tables<<<(S_LEN * 64 + 255) / 256, 256, 0, stream>>>(pos, cost, sint);

    // 2. split x
    split2<<<(S_LEN * DMODEL / 4 + 255) / 256, 256, 0, stream>>>(x, XH, XL, (size_t)S_LEN * DMODEL / 4, 1.0f);

    // 3. split w_q ; 4. Q projection
    split2<<<(QDIM * DMODEL / 4 + 255) / 256, 256, 0, stream>>>(w_q, WH, WL, (size_t)QDIM * DMODEL / 4, 1.0f);
    gemm_split<<<dim3(QDIM / 128, S_LEN / 128), 256, 0, stream>>>(
        XH, XL, WH, WL, nullptr, nullptr, Q32, nullptr, nullptr, QDIM, DMODEL, 0);

    // 5. split w_k, w_v ; 6. fused KV projection (writes fp32 caches + bf16 v^T)
    split2<<<(KVDIM * DMODEL / 4 + 255) / 256, 256, 0, stream>>>(w_k, WKH, WKL, (size_t)KVDIM * DMODEL / 4, 1.0f);
    split2<<<(KVDIM * DMODEL / 4 + 255) / 256, 256, 0, stream>>>(w_v, WVH, WVL, (size_t)KVDIM * DMODEL / 4, 1.0f);
    gemm_split<<<dim3(2 * KVDIM / 128, S_LEN / 128), 256, 0, stream>>>(
        XH, XL, WKH, WKL, WVH, WVL, out_k, out_v, VT, KVDIM, DMODEL, 1);

    // 7. RoPE
    rope_apply_q<<<(S_LEN * NH * 64) / 256, 256, 0, stream>>>(Q32, cost, sint);
    rope_apply_k<<<(NKV * S_LEN * 64) / 256, 256, 0, stream>>>(out_k, cost, sint);

    // 8. split q (pre-scaled) and k
    split2<<<(S_LEN * QDIM / 4 + 255) / 256, 256, 0, stream>>>(Q32, QH, QL, (size_t)S_LEN * QDIM / 4, QK_SCALE);
    split2<<<(NKV * S_LEN * HD / 4 + 255) / 256, 256, 0, stream>>>(out_k, KH, KL, (size_t)NKV * S_LEN * HD / 4, 1.0f);

    // 9. attention -> AO32 (reuses Q32 buffer; attn reads only QH/QL)
    attn_mfma<<<dim3(S_LEN / 64, NH), 256, 0, stream>>>(QH, QL, KH, KL, VT, AO32);

    // 10. split w_o ; 11. split ao ; 12. O projection
    split2<<<(DMODEL * QDIM / 4 + 255) / 256, 256, 0, stream>>>(w_o, WH, WL, (size_t)DMODEL * QDIM / 4, 1.0f);
    split2<<<(S_LEN * QDIM / 4 + 255) / 256, 256, 0, stream>>>(AO32, AOH, AOL, (size_t)S_LEN * QDIM / 4, 1.0f);
    gemm_split<<<dim3(DMODEL / 128, S_LEN / 128), 256, 0, stream>>>(
        AOH, AOL, WH, WL, nullptr, nullptr, out, nullptr, nullptr, DMODEL, QDIM, 0);
}

// Round 3
// 677.759 us; speedup vs baseline: 6.0584x; 1.0271x over previous
//
#include <hip/hip_runtime.h>
#include <math.h>

#define S_LEN 2048
#define DMODEL 2560
#define NH 32
#define NKV 8
#define HD 128
#define QDIM (NH*HD)     // 4096
#define KVDIM (NKV*HD)   // 1024
#define ROPE_THETA 5000000.0
#define QK_SCALE 0.08838834764831843f

typedef __attribute__((ext_vector_type(8))) short s16x8;
typedef __attribute__((ext_vector_type(4))) float f32x4;
typedef unsigned short u16;

#define MFMA16(a,b,c) __builtin_amdgcn_mfma_f32_16x16x32_bf16((a),(b),(c),0,0,0)

__device__ __forceinline__ u16 f2bf(float x) {
    union { float f; unsigned u; } v; v.f = x;
    unsigned r = v.u + 0x7FFFu + ((v.u >> 16) & 1u);
    return (u16)(r >> 16);
}
__device__ __forceinline__ float bf2f(u16 h) {
    union { unsigned u; float f; } v; v.u = ((unsigned)h) << 16;
    return v.f;
}

// Swizzled LDS index: row-major [rows][CKU*8] bf16; unit = 8 bf16 (16B).
// XOR low-3 bits of unit index with row&7 -> conflict-free b128 column reads.
__device__ __forceinline__ int lsw(int row, int kb, int CKU) {
    return (((row * CKU + kb) ^ (row & 7)) << 3);   // u16 element index
}

// async global->LDS, 16B per lane; LDS dest = wave-uniform base + lane*16.
__device__ __forceinline__ void gload16(const void* g, void* l) {
    __builtin_amdgcn_global_load_lds(
        (const __attribute__((address_space(1))) void*)g,
        (__attribute__((address_space(3))) void*)l, 16, 0, 0);
}

// ---------------------------------------------------------------------------
// RoPE tables (fp64-accurate range reduction)
// ---------------------------------------------------------------------------
__global__ void rope_tables(const int* __restrict__ pos_ids,
                            float* __restrict__ cost, float* __restrict__ sint) {
    int idx = blockIdx.x * 256 + threadIdx.x;
    if (idx >= S_LEN * 64) return;
    int s = idx >> 6, j = idx & 63;
    double inv = pow((double)ROPE_THETA, -(double)j / 64.0);
    double ang = (double)pos_ids[s] * inv;
    cost[idx] = (float)cos(ang);
    sint[idx] = (float)sin(ang);
}

// fused: rope(q) * QK_SCALE -> split hi/lo bf16
__global__ void rope_q_split(const float* __restrict__ q32,
                             const float* __restrict__ cost, const float* __restrict__ sint,
                             u16* __restrict__ qhh, u16* __restrict__ qll) {
    int idx = blockIdx.x * 256 + threadIdx.x;   // S_LEN*NH*64
    int j = idx & 63;
    int h = (idx >> 6) & 31;
    int s = idx >> 11;
    float c = cost[(s << 6) + j], sn = sint[(s << 6) + j];
    size_t base = (size_t)s * QDIM + (size_t)h * HD;
    float x1 = q32[base + j], x2 = q32[base + 64 + j];
    float y1 = (x1 * c - x2 * sn) * QK_SCALE;
    float y2 = (x2 * c + x1 * sn) * QK_SCALE;
    u16 h1 = f2bf(y1), h2 = f2bf(y2);
    qhh[base + j] = h1;      qll[base + j] = f2bf(y1 - bf2f(h1));
    qhh[base + 64 + j] = h2; qll[base + 64 + j] = f2bf(y2 - bf2f(h2));
}

// fused: rope(k) in place (fp32 cache output) + split hi/lo bf16
__global__ void rope_k_split(float* __restrict__ k,
                             const float* __restrict__ cost, const float* __restrict__ sint,
                             u16* __restrict__ khh, u16* __restrict__ kll) {
    int idx = blockIdx.x * 256 + threadIdx.x;   // NKV*S_LEN*64
    int j = idx & 63;
    int s = (idx >> 6) & 2047;
    int h = idx >> 17;
    float c = cost[(s << 6) + j], sn = sint[(s << 6) + j];
    size_t base = ((size_t)h * S_LEN + s) * HD;
    float x1 = k[base + j], x2 = k[base + 64 + j];
    float y1 = x1 * c - x2 * sn;
    float y2 = x2 * c + x1 * sn;
    k[base + j] = y1; k[base + 64 + j] = y2;
    u16 h1 = f2bf(y1), h2 = f2bf(y2);
    khh[base + j] = h1;      kll[base + j] = f2bf(y1 - bf2f(h1));
    khh[base + 64 + j] = h2; kll[base + 64 + j] = f2bf(y2 - bf2f(h2));
}

// ---------------------------------------------------------------------------
// split fp32 -> bf16 hi/lo
// ---------------------------------------------------------------------------
__global__ void split2(const float* __restrict__ in, u16* __restrict__ hi,
                       u16* __restrict__ lo, size_t n4) {
    size_t i = (size_t)blockIdx.x * 256 + threadIdx.x;
    if (i >= n4) return;
    float4 v = ((const float4*)in)[i];
    float a[4] = {v.x, v.y, v.z, v.w};
    u16 hh[4], ll[4];
    #pragma unroll
    for (int j = 0; j < 4; ++j) {
        hh[j] = f2bf(a[j]);
        ll[j] = f2bf(a[j] - bf2f(hh[j]));
    }
    ((uint2*)hi)[i] = make_uint2((unsigned)hh[0] | ((unsigned)hh[1] << 16),
                                 (unsigned)hh[2] | ((unsigned)hh[3] << 16));
    ((uint2*)lo)[i] = make_uint2((unsigned)ll[0] | ((unsigned)ll[1] << 16),
                                 (unsigned)ll[2] | ((unsigned)ll[3] << 16));
}

// fp32 -> bf16 (hi only)
__global__ void cvt_bf(const float* __restrict__ in, u16* __restrict__ out, size_t n4) {
    size_t i = (size_t)blockIdx.x * 256 + threadIdx.x;
    if (i >= n4) return;
    float4 v = ((const float4*)in)[i];
    u16 h0 = f2bf(v.x), h1 = f2bf(v.y), h2 = f2bf(v.z), h3 = f2bf(v.w);
    ((uint2*)out)[i] = make_uint2((unsigned)h0 | ((unsigned)h1 << 16),
                                  (unsigned)h2 | ((unsigned)h3 << 16));
}

// ---------------------------------------------------------------------------
// Split-bf16 MFMA GEMM (NT): C[m][n] = sum_k A[m][k]B[n][k]. 128x128, BK=64.
// mode 0: C1 row-major [M][N]. mode 1: fused KV -> cache layout; V blocks
// (blockIdx.x>=8) are single-term and also emit bf16 V^T into CT.
// nsplit: 3 = Ah*Bh + Ah*Bl + Al*Bh ; 1 = Ah*Bh only.
// ---------------------------------------------------------------------------
__global__ __launch_bounds__(256, 2)
void gemm_split(const u16* __restrict__ Ah, const u16* __restrict__ Al,
                const u16* __restrict__ B1h, const u16* __restrict__ B1l,
                const u16* __restrict__ B2h,
                float* __restrict__ C1, float* __restrict__ C2, u16* __restrict__ CT,
                int N, int K, int mode, int nsplit) {
    __shared__ u16 Ahs[128 * 64], Als[128 * 64], Bhs[128 * 64], Bls[128 * 64];
    const int tid = threadIdx.x;
    const int lane = tid & 63, w = tid >> 6;
    const int q4 = lane >> 4, r15 = lane & 15;
    const int m0 = blockIdx.y * 128;
    const int wm = (w >> 1) * 64, wn = (w & 1) * 64;

    const u16 *Bh, *Bl;
    float* C;
    int n0;
    bool wvt = false;
    if (mode == 0) {
        Bh = B1h; Bl = B1l; C = C1; n0 = blockIdx.x * 128;
    } else {
        bool isv = blockIdx.x >= 8;
        Bh = isv ? B2h : B1h; Bl = B1l;
        C = isv ? C2 : C1;
        n0 = (blockIdx.x & 7) * 128;
        wvt = isv;
        if (isv) nsplit = 1;
    }
    const bool full = (nsplit == 3);

    f32x4 acc[4][4];
    #pragma unroll
    for (int i = 0; i < 4; ++i)
        #pragma unroll
        for (int j = 0; j < 4; ++j) acc[i][j] = (f32x4)(0.0f);

    for (int k0 = 0; k0 < K; k0 += 64) {
        __syncthreads();
        // async staging: 16 chunks of 1KB per array; pre-swizzled source addr
        for (int ch = w; ch < 16; ch += 4) {
            int u = ch * 64 + lane;
            int row = u >> 3;
            int kb = (u & 7) ^ (row & 7);
            size_t goff = (size_t)row * K + k0 + kb * 8;
            gload16(Ah + (size_t)m0 * K + goff, &Ahs[ch * 512]);
            gload16(Bh + (size_t)n0 * K + goff, &Bhs[ch * 512]);
            if (full) {
                gload16(Al + (size_t)m0 * K + goff, &Als[ch * 512]);
                gload16(Bl + (size_t)n0 * K + goff, &Bls[ch * 512]);
            }
        }
        __syncthreads();   // drains vmcnt(0): LDS tiles ready

        #pragma unroll
        for (int kh2 = 0; kh2 < 2; ++kh2) {
            int kb = kh2 * 4 + q4;
            s16x8 ah[4], bh[4];
            #pragma unroll
            for (int i = 0; i < 4; ++i) ah[i] = *(const s16x8*)&Ahs[lsw(wm + i * 16 + r15, kb, 8)];
            #pragma unroll
            for (int j = 0; j < 4; ++j) bh[j] = *(const s16x8*)&Bhs[lsw(wn + j * 16 + r15, kb, 8)];
            if (full) {
                s16x8 al[4], bl2[4];
                #pragma unroll
                for (int i = 0; i < 4; ++i) al[i] = *(const s16x8*)&Als[lsw(wm + i * 16 + r15, kb, 8)];
                #pragma unroll
                for (int j = 0; j < 4; ++j) bl2[j] = *(const s16x8*)&Bls[lsw(wn + j * 16 + r15, kb, 8)];
                #pragma unroll
                for (int i = 0; i < 4; ++i)
                    #pragma unroll
                    for (int j = 0; j < 4; ++j) {
                        acc[i][j] = MFMA16(ah[i], bh[j], acc[i][j]);
                        acc[i][j] = MFMA16(ah[i], bl2[j], acc[i][j]);
                        acc[i][j] = MFMA16(al[i], bh[j], acc[i][j]);
                    }
            } else {
                #pragma unroll
                for (int i = 0; i < 4; ++i)
                    #pragma unroll
                    for (int j = 0; j < 4; ++j)
                        acc[i][j] = MFMA16(ah[i], bh[j], acc[i][j]);
            }
        }
    }

    // epilogue: D layout col = lane&15, row = (lane>>4)*4 + r  [m89-verified]
    #pragma unroll
    for (int i = 0; i < 4; ++i) {
        #pragma unroll
        for (int j = 0; j < 4; ++j) {
            int col = n0 + wn + j * 16 + r15;
            #pragma unroll
            for (int r = 0; r < 4; ++r) {
                int row = m0 + wm + i * 16 + q4 * 4 + r;
                float val = acc[i][j][r];
                if (mode == 0) {
                    C[(size_t)row * N + col] = val;
                } else {
                    int hh = col >> 7, d = col & 127;
                    C[((size_t)hh * S_LEN + row) * HD + d] = val;
                    if (wvt) CT[((size_t)hh * HD + d) * S_LEN + row] = f2bf(val);
                }
            }
        }
    }
}

// ---------------------------------------------------------------------------
// MFMA flash attention v2. Block: 512 thr = 2 heads x 4 waves, 64 q-rows/head.
// Grid: 512 blocks, bid&7 = kvh (XCD-locality for K/V in L2).
// qh/ql: [2048][4096] bf16 (pre-scaled); kh/kl: [8][2048][128]; vt: [8][128][2048]
// Output: bf16 ao [2048][4096].
// ---------------------------------------------------------------------------
__global__ __launch_bounds__(512, 4)
void attn_mfma2(const u16* __restrict__ qh, const u16* __restrict__ ql,
                const u16* __restrict__ kh, const u16* __restrict__ kl,
                const u16* __restrict__ vt, u16* __restrict__ aoh) {
    const int bid = blockIdx.x;
    const int kvh = bid & 7;
    const int rst = bid >> 3;
    const int qt = rst & 31;
    const int pair = rst >> 5;
    const int tid = threadIdx.x, lane = tid & 63, w = tid >> 6;
    const int head = kvh * 4 + pair * 2 + (w >> 2);
    const int wq = w & 3;                 // 16-row group within head
    const int q4 = lane >> 4, r15 = lane & 15;

    __shared__ u16 Khs[64 * 128], Kls[64 * 128];  // [64][128] swizzled, CKU=16
    __shared__ u16 Vts[128 * 64];                 // [128][64] swizzled, CKU=8
    __shared__ u16 Ps[2][64 * 64];                // per head-half
    u16* Psh = Ps[w >> 2];

    // Q fragments in registers
    s16x8 qfh[4], qfl[4];
    {
        size_t qrow = (size_t)qt * 64 + wq * 16 + r15;
        const u16* qb  = qh + qrow * QDIM + (size_t)head * HD + q4 * 8;
        const u16* qb2 = ql + qrow * QDIM + (size_t)head * HD + q4 * 8;
        #pragma unroll
        for (int db = 0; db < 4; ++db) {
            qfh[db] = *(const s16x8*)(qb + db * 32);
            qfl[db] = *(const s16x8*)(qb2 + db * 32);
        }
    }

    f32x4 acco[8];
    #pragma unroll
    for (int db = 0; db < 8; ++db) acco[db] = (f32x4)(0.0f);
    float mrow[4] = {-1e30f, -1e30f, -1e30f, -1e30f};
    float lrow[4] = {0.f, 0.f, 0.f, 0.f};

    const u16* kbase = kh + (size_t)kvh * S_LEN * HD;
    const u16* lbase = kl + (size_t)kvh * S_LEN * HD;
    const u16* vbase = vt + (size_t)kvh * HD * S_LEN;

    for (int kt = 0; kt <= qt; ++kt) {
        __syncthreads();   // all waves done reading previous tile's LDS
        // async stage K hi/lo [64][128] and V^T [128][64], pre-swizzled src
        for (int ch = w; ch < 16; ch += 8) {
            int u = ch * 64 + lane;
            int krow = u >> 4;
            int kb = (u & 15) ^ (krow & 7);
            size_t g = (size_t)(kt * 64 + krow) * HD + kb * 8;
            gload16(kbase + g, &Khs[ch * 512]);
            gload16(lbase + g, &Kls[ch * 512]);
            int vrow = u >> 3;
            int vb = (u & 7) ^ (vrow & 7);
            size_t gv = (size_t)vrow * S_LEN + kt * 64 + vb * 8;
            gload16(vbase + gv, &Vts[ch * 512]);
        }
        __syncthreads();   // vmcnt(0) drained: tiles ready

        // S = Q K^T (split: qh*kh + qh*kl + ql*kh)
        f32x4 sf[4];
        #pragma unroll
        for (int kf = 0; kf < 4; ++kf) sf[kf] = (f32x4)(0.0f);
        #pragma unroll
        for (int db = 0; db < 4; ++db) {
            int kb = db * 4 + q4;
            #pragma unroll
            for (int kf = 0; kf < 4; ++kf) {
                s16x8 bh = *(const s16x8*)&Khs[lsw(kf * 16 + r15, kb, 16)];
                s16x8 bl2 = *(const s16x8*)&Kls[lsw(kf * 16 + r15, kb, 16)];
                sf[kf] = MFMA16(qfh[db], bh, sf[kf]);
                sf[kf] = MFMA16(qfh[db], bl2, sf[kf]);
                sf[kf] = MFMA16(qfl[db], bh, sf[kf]);
            }
        }

        // causal mask (diagonal tile only)
        if (kt == qt) {
            #pragma unroll
            for (int kf = 0; kf < 4; ++kf) {
                int col = kf * 16 + r15;
                #pragma unroll
                for (int r = 0; r < 4; ++r) {
                    int rowg = wq * 16 + q4 * 4 + r;
                    if (col > rowg) sf[kf][r] = -1e30f;
                }
            }
        }

        // row max (16-lane groups hold rows)
        float pmax[4];
        #pragma unroll
        for (int r = 0; r < 4; ++r)
            pmax[r] = fmaxf(fmaxf(sf[0][r], sf[1][r]), fmaxf(sf[2][r], sf[3][r]));
        #pragma unroll
        for (int o = 1; o < 16; o <<= 1)
            #pragma unroll
            for (int r = 0; r < 4; ++r)
                pmax[r] = fmaxf(pmax[r], __shfl_xor(pmax[r], o));

        // defer-max: rescale only when max grew past threshold (T13)
        float dmax = fmaxf(fmaxf(pmax[0] - mrow[0], pmax[1] - mrow[1]),
                           fmaxf(pmax[2] - mrow[2], pmax[3] - mrow[3]));
        if (!__all(dmax <= 8.0f)) {
            #pragma unroll
            for (int r = 0; r < 4; ++r) {
                float mn = fmaxf(mrow[r], pmax[r]);
                float corr = __expf(mrow[r] - mn);
                mrow[r] = mn;
                lrow[r] *= corr;
                #pragma unroll
                for (int db = 0; db < 8; ++db) acco[db][r] *= corr;
            }
        }

        // P = exp(S - m), row-sum
        float rs[4];
        #pragma unroll
        for (int r = 0; r < 4; ++r) {
            float s0 = __expf(sf[0][r] - mrow[r]);
            float s1 = __expf(sf[1][r] - mrow[r]);
            float s2 = __expf(sf[2][r] - mrow[r]);
            float s3 = __expf(sf[3][r] - mrow[r]);
            sf[0][r] = s0; sf[1][r] = s1; sf[2][r] = s2; sf[3][r] = s3;
            rs[r] = (s0 + s1) + (s2 + s3);
        }
        #pragma unroll
        for (int o = 1; o < 16; o <<= 1)
            #pragma unroll
            for (int r = 0; r < 4; ++r)
                rs[r] += __shfl_xor(rs[r], o);
        #pragma unroll
        for (int r = 0; r < 4; ++r) lrow[r] += rs[r];

        // P -> LDS bf16 (wave-private rows; same-wave RAW)
        #pragma unroll
        for (int kf = 0; kf < 4; ++kf) {
            int col = kf * 16 + r15;
            #pragma unroll
            for (int r = 0; r < 4; ++r) {
                int prow = wq * 16 + q4 * 4 + r;
                Psh[lsw(prow, col >> 3, 8) + (col & 7)] = f2bf(sf[kf][r]);
            }
        }

        // O += P V
        s16x8 pa0 = *(const s16x8*)&Psh[lsw(wq * 16 + r15, q4, 8)];
        s16x8 pa1 = *(const s16x8*)&Psh[lsw(wq * 16 + r15, 4 + q4, 8)];
        #pragma unroll
        for (int db = 0; db < 8; ++db) {
            s16x8 vb0 = *(const s16x8*)&Vts[lsw(db * 16 + r15, q4, 8)];
            s16x8 vb1 = *(const s16x8*)&Vts[lsw(db * 16 + r15, 4 + q4, 8)];
            acco[db] = MFMA16(pa0, vb0, acco[db]);
            acco[db] = MFMA16(pa1, vb1, acco[db]);
        }
    }

    // epilogue: normalize and write bf16
    float inv[4];
    #pragma unroll
    for (int r = 0; r < 4; ++r) inv[r] = 1.0f / lrow[r];
    #pragma unroll
    for (int db = 0; db < 8; ++db)
        #pragma unroll
        for (int r = 0; r < 4; ++r) {
            size_t row = (size_t)qt * 64 + wq * 16 + q4 * 4 + r;
            aoh[row * QDIM + (size_t)head * HD + db * 16 + r15] = f2bf(acco[db][r] * inv[r]);
        }
}

// ---------------------------------------------------------------------------
extern "C" void kernel_launch(void* const* d_in, const int* in_sizes, int n_in,
                              void* d_out, int out_size, void* d_ws, size_t ws_size,
                              hipStream_t stream) {
    const float* x   = (const float*)d_in[0];
    const int*   pos = (const int*)d_in[1];
    const float* w_q = (const float*)d_in[2];
    const float* w_k = (const float*)d_in[3];
    const float* w_v = (const float*)d_in[4];
    const float* w_o = (const float*)d_in[5];

    float* out   = (float*)d_out;
    float* out_k = out + (size_t)S_LEN * DMODEL;
    float* out_v = out_k + (size_t)NKV * S_LEN * HD;

    // ---- workspace arena ----
    char* ws = (char*)d_ws;
    size_t off = 0;
    auto alloc = [&](size_t bytes) { char* p = ws + off; off += (bytes + 255) & ~255ull; return p; };
    float* cost = (float*)alloc((size_t)S_LEN * 64 * 4);
    float* sint = (float*)alloc((size_t)S_LEN * 64 * 4);
    float* Q32  = (float*)alloc((size_t)S_LEN * QDIM * 4);      // later: AOH (bf16)
    u16* XH  = (u16*)alloc((size_t)S_LEN * DMODEL * 2);         // later: KH
    u16* XL  = (u16*)alloc((size_t)S_LEN * DMODEL * 2);         // later: KL
    u16* WH  = (u16*)alloc((size_t)QDIM * DMODEL * 2);          // wq hi, later wo hi
    u16* WL  = (u16*)alloc((size_t)QDIM * DMODEL * 2);          // wq lo, later QH
    u16* WKH = (u16*)alloc((size_t)KVDIM * DMODEL * 2);
    u16* WKL = (u16*)alloc((size_t)KVDIM * DMODEL * 2);
    u16* WVH = (u16*)alloc((size_t)KVDIM * DMODEL * 2);
    u16* QL  = (u16*)alloc((size_t)S_LEN * QDIM * 2);
    u16* VT  = (u16*)alloc((size_t)NKV * HD * S_LEN * 2);
    u16* AOH = (u16*)Q32;     // alias: Q32 dead after rope_q_split
    u16* KH  = XH;            // alias: XH dead after KV gemm
    u16* KL  = XL;
    u16* QH  = WL;            // alias: WL dead after Q gemm

    // 1. RoPE tables
    rope_tables<<<(S_LEN * 64 + 255) / 256, 256, 0, stream>>>(pos, cost, sint);

    // 2. split x, w_q ; Q projection (split-3)
    split2<<<(S_LEN * DMODEL / 4 + 255) / 256, 256, 0, stream>>>(x, XH, XL, (size_t)S_LEN * DMODEL / 4);
    split2<<<(QDIM * DMODEL / 4 + 255) / 256, 256, 0, stream>>>(w_q, WH, WL, (size_t)QDIM * DMODEL / 4);
    gemm_split<<<dim3(QDIM / 128, S_LEN / 128), 256, 0, stream>>>(
        XH, XL, WH, WL, nullptr, Q32, nullptr, nullptr, QDIM, DMODEL, 0, 3);

    // 3. split w_k (3-term), convert w_v (1-term); fused KV projection
    split2<<<(KVDIM * DMODEL / 4 + 255) / 256, 256, 0, stream>>>(w_k, WKH, WKL, (size_t)KVDIM * DMODEL / 4);
    cvt_bf<<<(KVDIM * DMODEL / 4 + 255) / 256, 256, 0, stream>>>(w_v, WVH, (size_t)KVDIM * DMODEL / 4);
    gemm_split<<<dim3(2 * KVDIM / 128, S_LEN / 128), 256, 0, stream>>>(
        XH, XL, WKH, WKL, WVH, out_k, out_v, VT, KVDIM, DMODEL, 1, 3);

    // 4. fused rope+scale+split
    rope_q_split<<<(S_LEN * NH * 64) / 256, 256, 0, stream>>>(Q32, cost, sint, QH, QL);
    rope_k_split<<<(NKV * S_LEN * 64) / 256, 256, 0, stream>>>(out_k, cost, sint, KH, KL);

    // 5. attention -> bf16 AO
    attn_mfma2<<<512, 512, 0, stream>>>(QH, QL, KH, KL, VT, AOH);

    // 6. O projection (plain bf16)
    cvt_bf<<<(DMODEL * QDIM / 4 + 255) / 256, 256, 0, stream>>>(w_o, WH, (size_t)DMODEL * QDIM / 4);
    gemm_split<<<dim3(DMODEL / 128, S_LEN / 128), 256, 0, stream>>>(
        AOH, AOH, WH, WH, nullptr, out, nullptr, nullptr, DMODEL, QDIM, 0, 1);
}

// Round 4
// 488.250 us; speedup vs baseline: 8.4098x; 1.3881x over previous
//
#include <hip/hip_runtime.h>
#include <math.h>

#define S_LEN 2048
#define DMODEL 2560
#define NH 32
#define NKV 8
#define HD 128
#define QDIM (NH*HD)     // 4096
#define KVDIM (NKV*HD)   // 1024
#define ROPE_THETA 5000000.0
#define QK_SCALE 0.08838834764831843f

typedef __attribute__((ext_vector_type(8))) short s16x8;
typedef __attribute__((ext_vector_type(4))) float f32x4;
typedef unsigned short u16;

#define MFMA16(a,b,c) __builtin_amdgcn_mfma_f32_16x16x32_bf16((a),(b),(c),0,0,0)

__device__ __forceinline__ u16 f2bf(float x) {
    union { float f; unsigned u; } v; v.f = x;
    unsigned r = v.u + 0x7FFFu + ((v.u >> 16) & 1u);
    return (u16)(r >> 16);
}
__device__ __forceinline__ float bf2f(u16 h) {
    union { unsigned u; float f; } v; v.u = ((unsigned)h) << 16;
    return v.f;
}

// Swizzled LDS index: row-major [rows][CKU*8] bf16; unit = 8 bf16 (16B).
// XOR low-3 bits of unit index with row&7 -> conflict-free b128 column reads.
__device__ __forceinline__ int lsw(int row, int kb, int CKU) {
    return (((row * CKU + kb) ^ (row & 7)) << 3);   // u16 element index
}

// async global->LDS, 16B per lane; LDS dest = wave-uniform base + lane*16.
__device__ __forceinline__ void gload16(const void* g, void* l) {
    __builtin_amdgcn_global_load_lds(
        (const __attribute__((address_space(1))) void*)g,
        (__attribute__((address_space(3))) void*)l, 16, 0, 0);
}

// ---------------------------------------------------------------------------
// RoPE tables (fp64-accurate range reduction)
// ---------------------------------------------------------------------------
__global__ void rope_tables(const int* __restrict__ pos_ids,
                            float* __restrict__ cost, float* __restrict__ sint) {
    int idx = blockIdx.x * 256 + threadIdx.x;
    if (idx >= S_LEN * 64) return;
    int s = idx >> 6, j = idx & 63;
    double inv = pow((double)ROPE_THETA, -(double)j / 64.0);
    double ang = (double)pos_ids[s] * inv;
    cost[idx] = (float)cos(ang);
    sint[idx] = (float)sin(ang);
}

// fused: rope(q) * QK_SCALE -> split hi/lo bf16
__global__ void rope_q_split(const float* __restrict__ q32,
                             const float* __restrict__ cost, const float* __restrict__ sint,
                             u16* __restrict__ qhh, u16* __restrict__ qll) {
    int idx = blockIdx.x * 256 + threadIdx.x;   // S_LEN*NH*64
    int j = idx & 63;
    int h = (idx >> 6) & 31;
    int s = idx >> 11;
    float c = cost[(s << 6) + j], sn = sint[(s << 6) + j];
    size_t base = (size_t)s * QDIM + (size_t)h * HD;
    float x1 = q32[base + j], x2 = q32[base + 64 + j];
    float y1 = (x1 * c - x2 * sn) * QK_SCALE;
    float y2 = (x2 * c + x1 * sn) * QK_SCALE;
    u16 h1 = f2bf(y1), h2 = f2bf(y2);
    qhh[base + j] = h1;      qll[base + j] = f2bf(y1 - bf2f(h1));
    qhh[base + 64 + j] = h2; qll[base + 64 + j] = f2bf(y2 - bf2f(h2));
}

// fused: rope(k) in place (fp32 cache output) + split hi/lo bf16
__global__ void rope_k_split(float* __restrict__ k,
                             const float* __restrict__ cost, const float* __restrict__ sint,
                             u16* __restrict__ khh, u16* __restrict__ kll) {
    int idx = blockIdx.x * 256 + threadIdx.x;   // NKV*S_LEN*64
    int j = idx & 63;
    int s = (idx >> 6) & 2047;
    int h = idx >> 17;
    float c = cost[(s << 6) + j], sn = sint[(s << 6) + j];
    size_t base = ((size_t)h * S_LEN + s) * HD;
    float x1 = k[base + j], x2 = k[base + 64 + j];
    float y1 = x1 * c - x2 * sn;
    float y2 = x2 * c + x1 * sn;
    k[base + j] = y1; k[base + 64 + j] = y2;
    u16 h1 = f2bf(y1), h2 = f2bf(y2);
    khh[base + j] = h1;      kll[base + j] = f2bf(y1 - bf2f(h1));
    khh[base + 64 + j] = h2; kll[base + 64 + j] = f2bf(y2 - bf2f(h2));
}

// ---------------------------------------------------------------------------
// split fp32 -> bf16 hi/lo
// ---------------------------------------------------------------------------
__global__ void split2(const float* __restrict__ in, u16* __restrict__ hi,
                       u16* __restrict__ lo, size_t n4) {
    size_t i = (size_t)blockIdx.x * 256 + threadIdx.x;
    if (i >= n4) return;
    float4 v = ((const float4*)in)[i];
    float a[4] = {v.x, v.y, v.z, v.w};
    u16 hh[4], ll[4];
    #pragma unroll
    for (int j = 0; j < 4; ++j) {
        hh[j] = f2bf(a[j]);
        ll[j] = f2bf(a[j] - bf2f(hh[j]));
    }
    ((uint2*)hi)[i] = make_uint2((unsigned)hh[0] | ((unsigned)hh[1] << 16),
                                 (unsigned)hh[2] | ((unsigned)hh[3] << 16));
    ((uint2*)lo)[i] = make_uint2((unsigned)ll[0] | ((unsigned)ll[1] << 16),
                                 (unsigned)ll[2] | ((unsigned)ll[3] << 16));
}

// fp32 -> bf16 (hi only)
__global__ void cvt_bf(const float* __restrict__ in, u16* __restrict__ out, size_t n4) {
    size_t i = (size_t)blockIdx.x * 256 + threadIdx.x;
    if (i >= n4) return;
    float4 v = ((const float4*)in)[i];
    u16 h0 = f2bf(v.x), h1 = f2bf(v.y), h2 = f2bf(v.z), h3 = f2bf(v.w);
    ((uint2*)out)[i] = make_uint2((unsigned)h0 | ((unsigned)h1 << 16),
                                  (unsigned)h2 | ((unsigned)h3 << 16));
}

// ---------------------------------------------------------------------------
// V^T builder: v [8][2048][128] fp32 -> vt [8][128][2048] bf16.
// LDS-tiled 64x64; coalesced global on both sides (full-line writes).
// ---------------------------------------------------------------------------
__global__ __launch_bounds__(256)
void vt_transpose(const float* __restrict__ v, u16* __restrict__ vt) {
    __shared__ u16 t[64][80];
    const int kvh = blockIdx.y;
    const int st = blockIdx.x >> 1, dt = blockIdx.x & 1;
    const int tid = threadIdx.x;
    // read 64 s-rows x 64 d-cols fp32; lane: row=tid&15 per pass, col4=(tid>>4)*4
    const int r = tid & 15, c4 = (tid >> 4) * 4;
    const float* vb = v + ((size_t)kvh * S_LEN + st * 64) * HD + dt * 64;
    #pragma unroll
    for (int p = 0; p < 4; ++p) {
        int row = p * 16 + r;
        float4 x = *(const float4*)&vb[(size_t)row * HD + c4];
        t[c4 + 0][row] = f2bf(x.x);
        t[c4 + 1][row] = f2bf(x.y);
        t[c4 + 2][row] = f2bf(x.z);
        t[c4 + 3][row] = f2bf(x.w);
    }
    __syncthreads();
    // write: 64 d-rows x 128B each (full cachelines)
    #pragma unroll
    for (int p = 0; p < 2; ++p) {
        int idx = p * 256 + tid;
        int dr = idx >> 3, sc = idx & 7;
        size_t o = ((size_t)kvh * HD + dt * 64 + dr) * S_LEN + st * 64 + sc * 8;
        *(int4*)&vt[o] = *(const int4*)&t[dr][sc * 8];
    }
}

// ---------------------------------------------------------------------------
// Split-bf16 MFMA GEMM (NT): C[m][n] = sum_k A[m][k]B[n][k]. 128x128, BK=64.
// mode 0: C1 row-major [M][N]. mode 1: fused KV -> cache layout [8][2048][128];
// V blocks (blockIdx.x>=8) are single-term. nsplit: 3 or 1.
// ---------------------------------------------------------------------------
__global__ __launch_bounds__(256, 2)
void gemm_split(const u16* __restrict__ Ah, const u16* __restrict__ Al,
                const u16* __restrict__ B1h, const u16* __restrict__ B1l,
                const u16* __restrict__ B2h,
                float* __restrict__ C1, float* __restrict__ C2,
                int N, int K, int mode, int nsplit) {
    __shared__ u16 Ahs[128 * 64], Als[128 * 64], Bhs[128 * 64], Bls[128 * 64];
    const int tid = threadIdx.x;
    const int lane = tid & 63, w = tid >> 6;
    const int q4 = lane >> 4, r15 = lane & 15;
    const int m0 = blockIdx.y * 128;
    const int wm = (w >> 1) * 64, wn = (w & 1) * 64;

    const u16 *Bh, *Bl;
    float* C;
    int n0;
    if (mode == 0) {
        Bh = B1h; Bl = B1l; C = C1; n0 = blockIdx.x * 128;
    } else {
        bool isv = blockIdx.x >= 8;
        Bh = isv ? B2h : B1h; Bl = B1l;
        C = isv ? C2 : C1;
        n0 = (blockIdx.x & 7) * 128;
        if (isv) nsplit = 1;
    }
    const bool full = (nsplit == 3);

    f32x4 acc[4][4];
    #pragma unroll
    for (int i = 0; i < 4; ++i)
        #pragma unroll
        for (int j = 0; j < 4; ++j) acc[i][j] = (f32x4)(0.0f);

    for (int k0 = 0; k0 < K; k0 += 64) {
        __syncthreads();
        for (int ch = w; ch < 16; ch += 4) {
            int u = ch * 64 + lane;
            int row = u >> 3;
            int kb = (u & 7) ^ (row & 7);
            size_t goff = (size_t)row * K + k0 + kb * 8;
            gload16(Ah + (size_t)m0 * K + goff, &Ahs[ch * 512]);
            gload16(Bh + (size_t)n0 * K + goff, &Bhs[ch * 512]);
            if (full) {
                gload16(Al + (size_t)m0 * K + goff, &Als[ch * 512]);
                gload16(Bl + (size_t)n0 * K + goff, &Bls[ch * 512]);
            }
        }
        __syncthreads();   // drains vmcnt(0): LDS tiles ready

        #pragma unroll
        for (int kh2 = 0; kh2 < 2; ++kh2) {
            int kb = kh2 * 4 + q4;
            s16x8 ah[4], bh[4];
            #pragma unroll
            for (int i = 0; i < 4; ++i) ah[i] = *(const s16x8*)&Ahs[lsw(wm + i * 16 + r15, kb, 8)];
            #pragma unroll
            for (int j = 0; j < 4; ++j) bh[j] = *(const s16x8*)&Bhs[lsw(wn + j * 16 + r15, kb, 8)];
            if (full) {
                s16x8 al[4], bl2[4];
                #pragma unroll
                for (int i = 0; i < 4; ++i) al[i] = *(const s16x8*)&Als[lsw(wm + i * 16 + r15, kb, 8)];
                #pragma unroll
                for (int j = 0; j < 4; ++j) bl2[j] = *(const s16x8*)&Bls[lsw(wn + j * 16 + r15, kb, 8)];
                #pragma unroll
                for (int i = 0; i < 4; ++i)
                    #pragma unroll
                    for (int j = 0; j < 4; ++j) {
                        acc[i][j] = MFMA16(ah[i], bh[j], acc[i][j]);
                        acc[i][j] = MFMA16(ah[i], bl2[j], acc[i][j]);
                        acc[i][j] = MFMA16(al[i], bh[j], acc[i][j]);
                    }
            } else {
                #pragma unroll
                for (int i = 0; i < 4; ++i)
                    #pragma unroll
                    for (int j = 0; j < 4; ++j)
                        acc[i][j] = MFMA16(ah[i], bh[j], acc[i][j]);
            }
        }
    }

    // epilogue: D layout col = lane&15, row = (lane>>4)*4 + r
    #pragma unroll
    for (int i = 0; i < 4; ++i) {
        #pragma unroll
        for (int j = 0; j < 4; ++j) {
            int col = n0 + wn + j * 16 + r15;
            #pragma unroll
            for (int r = 0; r < 4; ++r) {
                int row = m0 + wm + i * 16 + q4 * 4 + r;
                float val = acc[i][j][r];
                if (mode == 0) {
                    C[(size_t)row * N + col] = val;
                } else {
                    int hh = col >> 7, d = col & 127;
                    C[((size_t)hh * S_LEN + row) * HD + d] = val;
                }
            }
        }
    }
}

// ---------------------------------------------------------------------------
// MFMA flash attention v3. 512 thr = 8 waves. Block handles 2 heads x
// 2 causally-paired q-tiles (qtA=qpair, qtB=31-qpair -> constant 33 computes).
// Grid 256 blocks (1/CU, LDS-forced). Double-buffered K/V via global_load_lds.
// ---------------------------------------------------------------------------
__global__ __launch_bounds__(512, 2)
void attn_mfma3(const u16* __restrict__ qh, const u16* __restrict__ ql,
                const u16* __restrict__ kh, const u16* __restrict__ kl,
                const u16* __restrict__ vt, u16* __restrict__ aoh) {
    const int bid = blockIdx.x;
    const int kvh = bid & 7;               // XCD-pinned under round-robin
    const int rest = bid >> 3;
    const int hp = rest & 1;
    const int qpair = rest >> 1;           // 0..15
    const int qtA = qpair, qtB = 31 - qpair;
    const int KTB = qtB + 1;

    const int tid = threadIdx.x, lane = tid & 63, w = tid >> 6;
    const int lh = w >> 2, wq = w & 3;
    const int head = kvh * 4 + hp * 2 + lh;
    const int q4 = lane >> 4, r15 = lane & 15;

    __shared__ u16 Khs[2][64 * 128], Kls[2][64 * 128];   // 32KB + 32KB
    __shared__ u16 Vts[2][128 * 64];                     // 32KB
    __shared__ u16 Ps[2][64 * 64];                       // 16KB
    u16* Psh = Ps[lh];

    // Q fragments (both q-tiles) in registers
    s16x8 qfh[2][4], qfl[2][4];
    #pragma unroll
    for (int t = 0; t < 2; ++t) {
        int qt = t ? qtB : qtA;
        size_t qrow = (size_t)qt * 64 + wq * 16 + r15;
        const u16* qb  = qh + qrow * QDIM + (size_t)head * HD + q4 * 8;
        const u16* qb2 = ql + qrow * QDIM + (size_t)head * HD + q4 * 8;
        #pragma unroll
        for (int db = 0; db < 4; ++db) {
            qfh[t][db] = *(const s16x8*)(qb + db * 32);
            qfl[t][db] = *(const s16x8*)(qb2 + db * 32);
        }
    }

    f32x4 acco[2][8];
    float mrow[2][4], lrow[2][4];
    #pragma unroll
    for (int t = 0; t < 2; ++t) {
        #pragma unroll
        for (int db = 0; db < 8; ++db) acco[t][db] = (f32x4)(0.0f);
        #pragma unroll
        for (int r = 0; r < 4; ++r) { mrow[t][r] = -1e30f; lrow[t][r] = 0.f; }
    }

    const u16* kbase = kh + (size_t)kvh * S_LEN * HD;
    const u16* lbase = kl + (size_t)kvh * S_LEN * HD;
    const u16* vbase = vt + (size_t)kvh * HD * S_LEN;

    auto stage = [&](int kt, int buf) {
        for (int c = w; c < 48; c += 8) {
            int c15 = c & 15;
            int u = c15 * 64 + lane;
            if (c < 32) {
                int krow = u >> 4;
                int kb = (u & 15) ^ (krow & 7);
                size_t g = (size_t)(kt * 64 + krow) * HD + kb * 8;
                const u16* src = (c < 16 ? kbase : lbase) + g;
                u16* dst = (c < 16 ? &Khs[buf][c15 * 512] : &Kls[buf][c15 * 512]);
                gload16(src, dst);
            } else {
                int vrow = u >> 3;
                int vb2 = (u & 7) ^ (vrow & 7);
                gload16(vbase + (size_t)vrow * S_LEN + kt * 64 + vb2 * 8,
                        &Vts[buf][c15 * 512]);
            }
        }
    };

    stage(0, 0);
    __syncthreads();   // vmcnt(0) drained

    for (int kt = 0; kt < KTB; ++kt) {
        const int cur = kt & 1;
        if (kt + 1 < KTB) stage(kt + 1, cur ^ 1);   // async prefetch, hidden

        #pragma unroll
        for (int t = 0; t < 2; ++t) {
            const int qt = t ? qtB : qtA;
            if (t == 0 && kt > qtA) continue;

            // S = Q K^T (split: qh*kh + qh*kl + ql*kh)
            f32x4 sf[4];
            #pragma unroll
            for (int kf = 0; kf < 4; ++kf) sf[kf] = (f32x4)(0.0f);
            #pragma unroll
            for (int db = 0; db < 4; ++db) {
                int kb = db * 4 + q4;
                #pragma unroll
                for (int kf = 0; kf < 4; ++kf) {
                    s16x8 bh  = *(const s16x8*)&Khs[cur][lsw(kf * 16 + r15, kb, 16)];
                    s16x8 bl2 = *(const s16x8*)&Kls[cur][lsw(kf * 16 + r15, kb, 16)];
                    sf[kf] = MFMA16(qfh[t][db], bh, sf[kf]);
                    sf[kf] = MFMA16(qfh[t][db], bl2, sf[kf]);
                    sf[kf] = MFMA16(qfl[t][db], bh, sf[kf]);
                }
            }

            if (kt == qt) {   // diagonal mask
                #pragma unroll
                for (int kf = 0; kf < 4; ++kf) {
                    int col = kf * 16 + r15;
                    #pragma unroll
                    for (int r = 0; r < 4; ++r) {
                        int rowg = wq * 16 + q4 * 4 + r;
                        if (col > rowg) sf[kf][r] = -1e30f;
                    }
                }
            }

            // row max over 16-lane group
            float pmax[4];
            #pragma unroll
            for (int r = 0; r < 4; ++r)
                pmax[r] = fmaxf(fmaxf(sf[0][r], sf[1][r]), fmaxf(sf[2][r], sf[3][r]));
            #pragma unroll
            for (int o = 1; o < 16; o <<= 1)
                #pragma unroll
                for (int r = 0; r < 4; ++r)
                    pmax[r] = fmaxf(pmax[r], __shfl_xor(pmax[r], o));

            // defer-max (T13)
            float dmax = fmaxf(fmaxf(pmax[0] - mrow[t][0], pmax[1] - mrow[t][1]),
                               fmaxf(pmax[2] - mrow[t][2], pmax[3] - mrow[t][3]));
            if (!__all(dmax <= 8.0f)) {
                #pragma unroll
                for (int r = 0; r < 4; ++r) {
                    float mn = fmaxf(mrow[t][r], pmax[r]);
                    float corr = __expf(mrow[t][r] - mn);
                    mrow[t][r] = mn;
                    lrow[t][r] *= corr;
                    #pragma unroll
                    for (int db = 0; db < 8; ++db) acco[t][db][r] *= corr;
                }
            }

            // P = exp(S - m); row-sum
            float rs[4];
            #pragma unroll
            for (int r = 0; r < 4; ++r) {
                float s0 = __expf(sf[0][r] - mrow[t][r]);
                float s1 = __expf(sf[1][r] - mrow[t][r]);
                float s2 = __expf(sf[2][r] - mrow[t][r]);
                float s3 = __expf(sf[3][r] - mrow[t][r]);
                sf[0][r] = s0; sf[1][r] = s1; sf[2][r] = s2; sf[3][r] = s3;
                rs[r] = (s0 + s1) + (s2 + s3);
            }
            #pragma unroll
            for (int o = 1; o < 16; o <<= 1)
                #pragma unroll
                for (int r = 0; r < 4; ++r)
                    rs[r] += __shfl_xor(rs[r], o);
            #pragma unroll
            for (int r = 0; r < 4; ++r) lrow[t][r] += rs[r];

            // P -> LDS bf16 (wave-private rows; same-wave RAW)
            #pragma unroll
            for (int kf = 0; kf < 4; ++kf) {
                int col = kf * 16 + r15;
                #pragma unroll
                for (int r = 0; r < 4; ++r) {
                    int prow = wq * 16 + q4 * 4 + r;
                    Psh[lsw(prow, col >> 3, 8) + (col & 7)] = f2bf(sf[kf][r]);
                }
            }

            // O += P V
            s16x8 pa0 = *(const s16x8*)&Psh[lsw(wq * 16 + r15, q4, 8)];
            s16x8 pa1 = *(const s16x8*)&Psh[lsw(wq * 16 + r15, 4 + q4, 8)];
            #pragma unroll
            for (int db = 0; db < 8; ++db) {
                s16x8 vb0 = *(const s16x8*)&Vts[cur][lsw(db * 16 + r15, q4, 8)];
                s16x8 vb1 = *(const s16x8*)&Vts[cur][lsw(db * 16 + r15, 4 + q4, 8)];
                acco[t][db] = MFMA16(pa0, vb0, acco[t][db]);
                acco[t][db] = MFMA16(pa1, vb1, acco[t][db]);
            }
        }

        __syncthreads();  // vmcnt(0): next tile staged; all waves done with cur
    }

    // epilogue: normalize, pack bf16 rows in LDS scratch, coalesced store
    u16* scr = ((u16*)Khs) + w * 2048;    // 4KB private per wave
    #pragma unroll
    for (int t = 0; t < 2; ++t) {
        const int qt = t ? qtB : qtA;
        float inv[4];
        #pragma unroll
        for (int r = 0; r < 4; ++r) inv[r] = 1.0f / lrow[t][r];
        #pragma unroll
        for (int db = 0; db < 8; ++db)
            #pragma unroll
            for (int r = 0; r < 4; ++r)
                scr[(q4 * 4 + r) * 128 + db * 16 + r15] = f2bf(acco[t][db][r] * inv[r]);
        #pragma unroll
        for (int p = 0; p < 4; ++p) {
            int idx = p * 512 + lane * 8;
            int lr = idx >> 7, col = idx & 127;
            size_t grow = (size_t)qt * 64 + wq * 16 + lr;
            *(int4*)&aoh[grow * QDIM + (size_t)head * HD + col] = *(const int4*)&scr[idx];
        }
    }
}

// ---------------------------------------------------------------------------
extern "C" void kernel_launch(void* const* d_in, const int* in_sizes, int n_in,
                              void* d_out, int out_size, void* d_ws, size_t ws_size,
                              hipStream_t stream) {
    const float* x   = (const float*)d_in[0];
    const int*   pos = (const int*)d_in[1];
    const float* w_q = (const float*)d_in[2];
    const float* w_k = (const float*)d_in[3];
    const float* w_v = (const float*)d_in[4];
    const float* w_o = (const float*)d_in[5];

    float* out   = (float*)d_out;
    float* out_k = out + (size_t)S_LEN * DMODEL;
    float* out_v = out_k + (size_t)NKV * S_LEN * HD;

    // ---- workspace arena ----
    char* ws = (char*)d_ws;
    size_t off = 0;
    auto alloc = [&](size_t bytes) { char* p = ws + off; off += (bytes + 255) & ~255ull; return p; };
    float* cost = (float*)alloc((size_t)S_LEN * 64 * 4);
    float* sint = (float*)alloc((size_t)S_LEN * 64 * 4);
    float* Q32  = (float*)alloc((size_t)S_LEN * QDIM * 4);      // later: AOH (bf16)
    u16* XH  = (u16*)alloc((size_t)S_LEN * DMODEL * 2);         // later: KH
    u16* XL  = (u16*)alloc((size_t)S_LEN * DMODEL * 2);         // later: KL
    u16* WH  = (u16*)alloc((size_t)QDIM * DMODEL * 2);          // wq hi, later wo hi
    u16* WL  = (u16*)alloc((size_t)QDIM * DMODEL * 2);          // wq lo, later QH
    u16* WKH = (u16*)alloc((size_t)KVDIM * DMODEL * 2);
    u16* WKL = (u16*)alloc((size_t)KVDIM * DMODEL * 2);
    u16* WVH = (u16*)alloc((size_t)KVDIM * DMODEL * 2);
    u16* QL  = (u16*)alloc((size_t)S_LEN * QDIM * 2);
    u16* VT  = (u16*)alloc((size_t)NKV * HD * S_LEN * 2);
    u16* AOH = (u16*)Q32;     // alias: Q32 dead after rope_q_split
    u16* KH  = XH;            // alias: XH dead after KV gemm
    u16* KL  = XL;
    u16* QH  = WL;            // alias: WL dead after Q gemm

    // 1. RoPE tables
    rope_tables<<<(S_LEN * 64 + 255) / 256, 256, 0, stream>>>(pos, cost, sint);

    // 2. split x, w_q ; Q projection (split-3)
    split2<<<(S_LEN * DMODEL / 4 + 255) / 256, 256, 0, stream>>>(x, XH, XL, (size_t)S_LEN * DMODEL / 4);
    split2<<<(QDIM * DMODEL / 4 + 255) / 256, 256, 0, stream>>>(w_q, WH, WL, (size_t)QDIM * DMODEL / 4);
    gemm_split<<<dim3(QDIM / 128, S_LEN / 128), 256, 0, stream>>>(
        XH, XL, WH, WL, nullptr, Q32, nullptr, QDIM, DMODEL, 0, 3);

    // 3. split w_k (3-term), convert w_v (1-term); fused KV projection
    split2<<<(KVDIM * DMODEL / 4 + 255) / 256, 256, 0, stream>>>(w_k, WKH, WKL, (size_t)KVDIM * DMODEL / 4);
    cvt_bf<<<(KVDIM * DMODEL / 4 + 255) / 256, 256, 0, stream>>>(w_v, WVH, (size_t)KVDIM * DMODEL / 4);
    gemm_split<<<dim3(2 * KVDIM / 128, S_LEN / 128), 256, 0, stream>>>(
        XH, XL, WKH, WKL, WVH, out_k, out_v, KVDIM, DMODEL, 1, 3);

    // 4. V^T (coalesced transpose) + fused rope+scale+split
    vt_transpose<<<dim3(64, 8), 256, 0, stream>>>(out_v, VT);
    rope_q_split<<<(S_LEN * NH * 64) / 256, 256, 0, stream>>>(Q32, cost, sint, QH, QL);
    rope_k_split<<<(NKV * S_LEN * 64) / 256, 256, 0, stream>>>(out_k, cost, sint, KH, KL);

    // 5. attention -> bf16 AO
    attn_mfma3<<<256, 512, 0, stream>>>(QH, QL, KH, KL, VT, AOH);

    // 6. O projection (plain bf16)
    cvt_bf<<<(DMODEL * QDIM / 4 + 255) / 256, 256, 0, stream>>>(w_o, WH, (size_t)DMODEL * QDIM / 4);
    gemm_split<<<dim3(DMODEL / 128, S_LEN / 128), 256, 0, stream>>>(
        AOH, AOH, WH, WH, nullptr, out, nullptr, DMODEL, QDIM, 0, 1);
}